// Round 2
// baseline (535.877 us; speedup 1.0000x reference)
//
#include <hip/hip_runtime.h>

// Problem geometry (fixed by the reference): img [1,1,160,192,224] fp32,
// phi [1,3,160,192,224] fp32, out [1,1,160,192,224] fp32.
// Reference math: grid = phi*2-1 ; coord_d = clip((grid_d+1)*0.5*(sz_d-1), 0, sz_d-1)
// then trilinear sample with border clamp (only upper corner needs min()).

#define DD 160
#define HH 192
#define WW 224

__global__ __launch_bounds__(256) void vm_gridsample_kernel(
    const float* __restrict__ img,
    const float* __restrict__ phi,
    float* __restrict__ out,
    int n) {
  int i = blockIdx.x * blockDim.x + threadIdx.x;
  if (i >= n) return;

  const int N = DD * HH * WW;

  // phi channels are planar: [3, D*H*W] — three coalesced streams.
  // Read-once data: nontemporal to avoid evicting img from L2/L3.
  float p0 = __builtin_nontemporal_load(&phi[i]);
  float p1 = __builtin_nontemporal_load(&phi[i + N]);
  float p2 = __builtin_nontemporal_load(&phi[i + 2 * N]);

  // Replicate reference arithmetic exactly: (p*2-1+1)*0.5*(sz-1), then clip.
  float cx = (p0 * 2.0f - 1.0f + 1.0f) * 0.5f * (float)(DD - 1);
  float cy = (p1 * 2.0f - 1.0f + 1.0f) * 0.5f * (float)(HH - 1);
  float cz = (p2 * 2.0f - 1.0f + 1.0f) * 0.5f * (float)(WW - 1);
  cx = fminf(fmaxf(cx, 0.0f), (float)(DD - 1));
  cy = fminf(fmaxf(cy, 0.0f), (float)(HH - 1));
  cz = fminf(fmaxf(cz, 0.0f), (float)(WW - 1));

  float x0f = floorf(cx), y0f = floorf(cy), z0f = floorf(cz);
  float fx = cx - x0f, fy = cy - y0f, fz = cz - z0f;

  int x0 = (int)x0f, y0 = (int)y0f, z0 = (int)z0f;
  int x1 = min(x0 + 1, DD - 1);
  int y1 = min(y0 + 1, HH - 1);
  int z1 = min(z0 + 1, WW - 1);

  // 4 row bases; z-pairs are adjacent in memory.
  int b00 = (x0 * HH + y0) * WW;
  int b01 = (x0 * HH + y1) * WW;
  int b10 = (x1 * HH + y0) * WW;
  int b11 = (x1 * HH + y1) * WW;

  float v000 = img[b00 + z0];
  float v001 = img[b00 + z1];
  float v010 = img[b01 + z0];
  float v011 = img[b01 + z1];
  float v100 = img[b10 + z0];
  float v101 = img[b10 + z1];
  float v110 = img[b11 + z0];
  float v111 = img[b11 + z1];

  float gx0 = 1.0f - fx, gy0 = 1.0f - fy, gz0 = 1.0f - fz;

  float c00 = v000 * gz0 + v001 * fz;
  float c01 = v010 * gz0 + v011 * fz;
  float c10 = v100 * gz0 + v101 * fz;
  float c11 = v110 * gz0 + v111 * fz;

  float c0 = c00 * gy0 + c01 * fy;
  float c1 = c10 * gy0 + c11 * fy;

  // Write-once stream: nontemporal store.
  __builtin_nontemporal_store(c0 * gx0 + c1 * fx, &out[i]);
}

extern "C" void kernel_launch(void* const* d_in, const int* in_sizes, int n_in,
                              void* d_out, int out_size, void* d_ws, size_t ws_size,
                              hipStream_t stream) {
  const float* img = (const float*)d_in[0];  // [1,1,160,192,224]
  const float* phi = (const float*)d_in[1];  // [1,3,160,192,224]
  float* out = (float*)d_out;                // [1,1,160,192,224]

  int n = DD * HH * WW;  // 6,881,280
  int block = 256;
  int grid = (n + block - 1) / block;
  vm_gridsample_kernel<<<grid, block, 0, stream>>>(img, phi, out, n);
}